// Round 5
// baseline (317.535 us; speedup 1.0000x reference)
//
#include <hip/hip_runtime.h>
#include <hip/hip_bf16.h>

// B=8192, N=M=K=2048, H=10.
// Pipeline (5 launches):
//   1) pre_kernel: [col-sum partials] + [row sums of W] + [X -> per-row-scaled
//      2-level int8 split X1,X2 + sx1 row scales]
//   2) nca_update: finish col sums, per-cell MLP, write Wt = new_weight^T (fp32)
//      (MLP weights read directly as uniform global loads -> s_load)
//   3) bquant: per-row (=Wn column) 2-level int8 quantize of Wt -> B1,B2,sw1
//   4) i8 MFMA GEMM — register double-buffered fragments.
//      128x128 tile, 4 waves (2Mx2N, 64x64/wave), 4x32KB LDS buffers,
//      depth-3 staging (counted vmcnt(8)), ONE barrier/tile. Each step:
//      MFMA on frag set X (ds_reads issued LAST step, lgkm-waited now for
//      free) overlaps ds_reads of tile i+1 into set Y + staging of tile i+3.
//      ROUND 5: lgkmcnt(16) -> lgkmcnt(15) (4-bit field, max 15; drains all
//      16 older CUR reads + 1 new NXT read — negligibly stronger wait).
//   5) row softmax (one wave/row), applying sx1[row] on load.

typedef int int4v __attribute__((ext_vector_type(4)));
typedef int int16v __attribute__((ext_vector_type(16)));

#define GK 2048
#define NROWS 2048
#define MCOLS 2048
#define NCHUNK 16

// ---------------- fused pre-pass --------------------------------------------
#define CS_BLOCKS 128
#define RS_BLOCKS 2048
__global__ __launch_bounds__(256) void pre_kernel(
    const float* __restrict__ X, const float* __restrict__ W,
    signed char* __restrict__ X1, signed char* __restrict__ X2,
    float* __restrict__ sx1,
    float* __restrict__ part, float* __restrict__ rowS) {
  const int bid = blockIdx.x;
  const int tid = threadIdx.x;

  if (bid < CS_BLOCKS) {
    int chunk = bid >> 3;                 // 0..15
    int j = (bid & 7) * 256 + tid;        // column
    int i0 = chunk * (NROWS / NCHUNK);
    float s = 0.f;
    for (int i = i0; i < i0 + NROWS / NCHUNK; ++i) s += W[(size_t)i * MCOLS + j];
    part[(size_t)chunk * MCOLS + j] = s;
    return;
  }
  if (bid < CS_BLOCKS + RS_BLOCKS) {
    int row = bid - CS_BLOCKS;
    const float4* p = (const float4*)(W + (size_t)row * MCOLS);
    float4 a = p[tid];
    float4 b = p[tid + 256];
    float v = (a.x + a.y) + (a.z + a.w) + (b.x + b.y) + (b.z + b.w);
    __shared__ float red[256];
    red[tid] = v;
    __syncthreads();
    for (int s = 128; s > 0; s >>= 1) {
      if (tid < s) red[tid] += red[tid + s];
      __syncthreads();
    }
    if (tid == 0) rowS[row] = red[0];
    return;
  }
  // X row quantization: one block per row, 8 elems/thread
  {
    int row = bid - CS_BLOCKS - RS_BLOCKS;
    const float4* xr = (const float4*)(X + (size_t)row * GK);
    float4 a = xr[tid * 2];
    float4 b = xr[tid * 2 + 1];
    float xs[8] = {a.x, a.y, a.z, a.w, b.x, b.y, b.z, b.w};
    float am = 0.f;
#pragma unroll
    for (int i = 0; i < 8; ++i) am = fmaxf(am, fabsf(xs[i]));
    const int lane = tid & 63, wv = tid >> 6;
#pragma unroll
    for (int off = 32; off > 0; off >>= 1)
      am = fmaxf(am, __shfl_xor(am, off));
    __shared__ float wred[4];
    if (lane == 0) wred[wv] = am;
    __syncthreads();
    float amax = fmaxf(fmaxf(wred[0], wred[1]), fmaxf(wred[2], wred[3]));
    float s1 = amax * (1.0f / 127.0f);
    float inv = 127.0f / amax;
    int q1[8], q2[8];
#pragma unroll
    for (int i = 0; i < 8; ++i) {
      q1[i] = (int)rintf(xs[i] * inv);
      float r = xs[i] - (float)q1[i] * s1;
      q2[i] = (int)rintf(r * (254.0f * inv));
    }
    unsigned lo1 = (q1[0] & 255) | ((q1[1] & 255) << 8) | ((q1[2] & 255) << 16) | ((q1[3] & 255) << 24);
    unsigned hi1 = (q1[4] & 255) | ((q1[5] & 255) << 8) | ((q1[6] & 255) << 16) | ((q1[7] & 255) << 24);
    unsigned lo2 = (q2[0] & 255) | ((q2[1] & 255) << 8) | ((q2[2] & 255) << 16) | ((q2[3] & 255) << 24);
    unsigned hi2 = (q2[4] & 255) | ((q2[5] & 255) << 8) | ((q2[6] & 255) << 16) | ((q2[7] & 255) << 24);
    ((uint2*)(X1 + (size_t)row * GK))[tid] = make_uint2(lo1, hi1);
    ((uint2*)(X2 + (size_t)row * GK))[tid] = make_uint2(lo2, hi2);
    if (tid == 0) sx1[row] = s1;
  }
}

// ------- NCA MLP -> new_weight, transposed fp32 out -------------------------
__global__ __launch_bounds__(256) void nca_update_kernel(
    const float* __restrict__ W, const float* __restrict__ part,
    const float* __restrict__ rowS,
    const float* __restrict__ W1, const float* __restrict__ b1,
    const float* __restrict__ W2, const float* __restrict__ b2,
    const float* __restrict__ W3, const float* __restrict__ b3,
    float* __restrict__ Wt) {
  __shared__ float sColS[32];
  __shared__ float cred[NCHUNK][33];
  __shared__ float Tf[32][33];
  const int tid = threadIdx.x;
  const int i0 = blockIdx.y * 32;
  const int j0 = blockIdx.x * 32;

  {
    int ch = tid >> 5;
    int jl = tid & 31;
    cred[ch][jl]     = part[(size_t)ch * MCOLS + j0 + jl];
    cred[ch + 8][jl] = part[(size_t)(ch + 8) * MCOLS + j0 + jl];
  }
  __syncthreads();
  if (tid < 32) {
    float s = 0.f;
#pragma unroll
    for (int c = 0; c < NCHUNK; ++c) s += cred[c][tid];
    sColS[tid] = s;
  }
  __syncthreads();

  const int r = tid >> 5;
  const int c = tid & 31;

  float w[4], fwd[4], bwd[4];
#pragma unroll
  for (int cell = 0; cell < 4; ++cell) {
    int il = r + 8 * cell;
    float wv = W[(size_t)(i0 + il) * MCOLS + j0 + c];
    w[cell] = wv;
    fwd[cell] = (sColS[c] - wv) * (1.0f / (float)(NROWS - 1));
    bwd[cell] = (rowS[i0 + il] - wv) * (1.0f / (float)(MCOLS - 1));
  }

  // MLP weights: direct uniform reads (scalarized by compiler; no LDS pipe)
  float h1[4][10];
#pragma unroll
  for (int o = 0; o < 10; ++o) {
    float w1a = W1[o], w1b = W1[10 + o], w1c = W1[20 + o], bb = b1[o];
#pragma unroll
    for (int cell = 0; cell < 4; ++cell) {
      float v = fmaf(w[cell], w1a, fmaf(fwd[cell], w1b, fmaf(bwd[cell], w1c, bb)));
      h1[cell][o] = fmaxf(v, 0.f);
    }
  }
  const float b3v = b3[0];
  float u[4] = {b3v, b3v, b3v, b3v};
#pragma unroll
  for (int o = 0; o < 10; ++o) {
    float h2[4];
    float bb = b2[o];
#pragma unroll
    for (int cell = 0; cell < 4; ++cell) h2[cell] = bb;
#pragma unroll
    for (int p = 0; p < 10; ++p) {
      float wv = W2[p * 10 + o];
#pragma unroll
      for (int cell = 0; cell < 4; ++cell) h2[cell] = fmaf(h1[cell][p], wv, h2[cell]);
    }
    float w3 = W3[o];
#pragma unroll
    for (int cell = 0; cell < 4; ++cell) u[cell] = fmaf(fmaxf(h2[cell], 0.f), w3, u[cell]);
  }

#pragma unroll
  for (int cell = 0; cell < 4; ++cell) {
    int il = r + 8 * cell;
    Tf[il][c] = w[cell] + u[cell];
  }
  __syncthreads();

  {
    int r2 = tid >> 4;          // 0..15
    int ic = (tid & 15) * 2;    // 0..30
#pragma unroll
    for (int half = 0; half < 2; ++half) {
      int jl = r2 + 16 * half;
      float2 v = make_float2(Tf[ic][jl], Tf[ic + 1][jl]);
      *(float2*)(&Wt[(size_t)(j0 + jl) * NROWS + i0 + ic]) = v;
    }
  }
}

// -------- B quantize: one block per Wt row (= Wn column) --------------------
__global__ __launch_bounds__(256) void bquant_kernel(
    const float* __restrict__ Wt, signed char* __restrict__ B1,
    signed char* __restrict__ B2, float* __restrict__ sw1) {
  const int row = blockIdx.x;
  const int tid = threadIdx.x;
  const float4* wr = (const float4*)(Wt + (size_t)row * GK);
  float4 a = wr[tid * 2];
  float4 b = wr[tid * 2 + 1];
  float xs[8] = {a.x, a.y, a.z, a.w, b.x, b.y, b.z, b.w};
  float am = 0.f;
#pragma unroll
  for (int i = 0; i < 8; ++i) am = fmaxf(am, fabsf(xs[i]));
  const int lane = tid & 63, wv = tid >> 6;
#pragma unroll
  for (int off = 32; off > 0; off >>= 1)
    am = fmaxf(am, __shfl_xor(am, off));
  __shared__ float wred[4];
  if (lane == 0) wred[wv] = am;
  __syncthreads();
  float amax = fmaxf(fmaxf(wred[0], wred[1]), fmaxf(wred[2], wred[3]));
  float s1 = amax * (1.0f / 127.0f);
  float inv = 127.0f / amax;
  int q1[8], q2[8];
#pragma unroll
  for (int i = 0; i < 8; ++i) {
    q1[i] = (int)rintf(xs[i] * inv);
    float r = xs[i] - (float)q1[i] * s1;
    q2[i] = (int)rintf(r * (254.0f * inv));
  }
  unsigned lo1 = (q1[0] & 255) | ((q1[1] & 255) << 8) | ((q1[2] & 255) << 16) | ((q1[3] & 255) << 24);
  unsigned hi1 = (q1[4] & 255) | ((q1[5] & 255) << 8) | ((q1[6] & 255) << 16) | ((q1[7] & 255) << 24);
  unsigned lo2 = (q2[0] & 255) | ((q2[1] & 255) << 8) | ((q2[2] & 255) << 16) | ((q2[3] & 255) << 24);
  unsigned hi2 = (q2[4] & 255) | ((q2[5] & 255) << 8) | ((q2[6] & 255) << 16) | ((q2[7] & 255) << 24);
  ((uint2*)(B1 + (size_t)row * GK))[tid] = make_uint2(lo1, hi1);
  ((uint2*)(B2 + (size_t)row * GK))[tid] = make_uint2(lo2, hi2);
  if (tid == 0) sw1[row] = s1;
}

// ------- register-double-buffered 2-level i8 MFMA GEMM ----------------------
// Tile 128x128, BK=64, 4 waves as 2Mx2N (64x64 output per wave).
// LDS: 4 buffers x 32KB (A1@0 A2@8K B1@16K B2@24K per buffer).
// 1KB block = 16 rows x 64B; slot s holds (row=s>>2, chunk=(s&3)^((s>>3)&3));
// staging wave w owns array w (A1,A2,B1,B2), 8 blocks x 1KB, lane l fetches
// row (l>>2), chunk (l&3)^((l>>3)&3) of its block -> pre-swizzled global src +
// linear gload_lds dest. Frag read (row rl, chunk c): slot=4*rl+(c^((rl>>1)&3)).
// Steady state at step i: MFMA on set CUR (reads issued step i-1), ds_read
// tile i+1 -> set NXT, stage tile i+3 (8 gloads), vmcnt(8) + 1 barrier/step.
#define BM 128
#define BN 128
#define BK 64
#define NT (GK / BK)
#define BUFSZ 32768
#define SROWSZ ((size_t)16 * GK)

__device__ __forceinline__ void glds16(const signed char* g, char* l) {
  __builtin_amdgcn_global_load_lds(
      (const __attribute__((address_space(1))) void*)g,
      (__attribute__((address_space(3))) void*)l, 16, 0, 0);
}

__device__ __forceinline__ int4v ds_read128(const char* p) {
  int4v r;
  asm volatile("ds_read_b128 %0, %1"
               : "=v"(r)
               : "v"((const __attribute__((address_space(3))) char*)p));
  return r;
}

#define MFMA_I8 __builtin_amdgcn_mfma_i32_32x32x32_i8

// 16 ds_read_b128 for one fragment set from buffer base rb_
#define RD16(NX, rb_)                                                          \
  NX##a1[0][0] = ds_read128((rb_) + aoff[0][0]);                               \
  NX##a1[0][1] = ds_read128((rb_) + aoff[0][1]);                               \
  NX##a1[1][0] = ds_read128((rb_) + aoff[1][0]);                               \
  NX##a1[1][1] = ds_read128((rb_) + aoff[1][1]);                               \
  NX##a2[0][0] = ds_read128((rb_) + aoff[0][0] + 8192);                        \
  NX##a2[0][1] = ds_read128((rb_) + aoff[0][1] + 8192);                        \
  NX##a2[1][0] = ds_read128((rb_) + aoff[1][0] + 8192);                        \
  NX##a2[1][1] = ds_read128((rb_) + aoff[1][1] + 8192);                        \
  NX##b1[0][0] = ds_read128((rb_) + boff[0][0]);                               \
  NX##b1[0][1] = ds_read128((rb_) + boff[0][1]);                               \
  NX##b1[1][0] = ds_read128((rb_) + boff[1][0]);                               \
  NX##b1[1][1] = ds_read128((rb_) + boff[1][1]);                               \
  NX##b2[0][0] = ds_read128((rb_) + boff[0][0] + 8192);                        \
  NX##b2[0][1] = ds_read128((rb_) + boff[0][1] + 8192);                        \
  NX##b2[1][0] = ds_read128((rb_) + boff[1][0] + 8192);                        \
  NX##b2[1][1] = ds_read128((rb_) + boff[1][1] + 8192);

// 24 MFMAs for one K-tile on set CUR; 8 independent-ish chains, dependent
// writes to the same acc spaced >= 4 apart.
#define MM12(CUR, ks)                                                          \
  acc_h[0][0] = MFMA_I8(CUR##a1[0][ks], CUR##b1[0][ks], acc_h[0][0], 0, 0, 0); \
  acc_h[0][1] = MFMA_I8(CUR##a1[0][ks], CUR##b1[1][ks], acc_h[0][1], 0, 0, 0); \
  acc_h[1][0] = MFMA_I8(CUR##a1[1][ks], CUR##b1[0][ks], acc_h[1][0], 0, 0, 0); \
  acc_h[1][1] = MFMA_I8(CUR##a1[1][ks], CUR##b1[1][ks], acc_h[1][1], 0, 0, 0); \
  acc_c[0][0] = MFMA_I8(CUR##a1[0][ks], CUR##b2[0][ks], acc_c[0][0], 0, 0, 0); \
  acc_c[0][1] = MFMA_I8(CUR##a1[0][ks], CUR##b2[1][ks], acc_c[0][1], 0, 0, 0); \
  acc_c[1][0] = MFMA_I8(CUR##a1[1][ks], CUR##b2[0][ks], acc_c[1][0], 0, 0, 0); \
  acc_c[1][1] = MFMA_I8(CUR##a1[1][ks], CUR##b2[1][ks], acc_c[1][1], 0, 0, 0); \
  acc_c[0][0] = MFMA_I8(CUR##a2[0][ks], CUR##b1[0][ks], acc_c[0][0], 0, 0, 0); \
  acc_c[0][1] = MFMA_I8(CUR##a2[0][ks], CUR##b1[1][ks], acc_c[0][1], 0, 0, 0); \
  acc_c[1][0] = MFMA_I8(CUR##a2[1][ks], CUR##b1[0][ks], acc_c[1][0], 0, 0, 0); \
  acc_c[1][1] = MFMA_I8(CUR##a2[1][ks], CUR##b1[1][ks], acc_c[1][1], 0, 0, 0);

#define STAGE8(wb_, gp_)                                                       \
  glds16((gp_) + 0 * SROWSZ, (wb_) + 0 * 1024 + lane * 16);                    \
  glds16((gp_) + 1 * SROWSZ, (wb_) + 1 * 1024 + lane * 16);                    \
  glds16((gp_) + 2 * SROWSZ, (wb_) + 2 * 1024 + lane * 16);                    \
  glds16((gp_) + 3 * SROWSZ, (wb_) + 3 * 1024 + lane * 16);                    \
  glds16((gp_) + 4 * SROWSZ, (wb_) + 4 * 1024 + lane * 16);                    \
  glds16((gp_) + 5 * SROWSZ, (wb_) + 5 * 1024 + lane * 16);                    \
  glds16((gp_) + 6 * SROWSZ, (wb_) + 6 * 1024 + lane * 16);                    \
  glds16((gp_) + 7 * SROWSZ, (wb_) + 7 * 1024 + lane * 16);

// one pipeline step: compute tile i on CUR, read tile i+1 into NXT,
// stage tile i+3, counted vmcnt/lgkm, one barrier.
// lgkmcnt(15): 4-bit field max; drains all 16 CUR reads (issued last step)
// plus 1 of the 16 NXT reads just issued — correct, marginally stronger.
#define STEP(i, CUR, NXT)                                                      \
  {                                                                            \
    if ((i) + 2 < NT) asm volatile("s_waitcnt vmcnt(8)" ::: "memory");         \
    else              asm volatile("s_waitcnt vmcnt(0)" ::: "memory");         \
    __builtin_amdgcn_s_barrier();                                              \
    if ((i) + 1 < NT) {                                                        \
      const char* rb_ = sL + (((i) + 1) & 3) * BUFSZ;                          \
      RD16(NXT, rb_);                                                          \
    }                                                                          \
    if ((i) + 3 < NT) {                                                        \
      char* wb_ = sL + (((i) + 3) & 3) * BUFSZ + wave * 8192;                  \
      const signed char* gp_ = gw + (size_t)((i) + 3) * BK;                    \
      STAGE8(wb_, gp_);                                                        \
    }                                                                          \
    if ((i) + 1 < NT) asm volatile("s_waitcnt lgkmcnt(15)" ::: "memory");      \
    else              asm volatile("s_waitcnt lgkmcnt(0)" ::: "memory");       \
    __builtin_amdgcn_sched_barrier(0);                                         \
    __builtin_amdgcn_s_setprio(1);                                             \
    MM12(CUR, 0);                                                              \
    MM12(CUR, 1);                                                              \
    __builtin_amdgcn_s_setprio(0);                                             \
  }

__global__ __launch_bounds__(256, 1) void gemm_kernel(
    const signed char* __restrict__ X1, const signed char* __restrict__ X2,
    const signed char* __restrict__ B1, const signed char* __restrict__ B2,
    const float* __restrict__ sw1, float* __restrict__ C) {
  __shared__ __align__(16) char sL[4 * BUFSZ];  // 128 KB

  const int tid = threadIdx.x;
  const int lane = tid & 63;
  const int wave = tid >> 6;   // 0..3
  const int wr = wave >> 1;    // 0..1 (M)
  const int wc = wave & 1;     // 0..1 (N)

  const int bx = blockIdx.x;   // 0..15
  const int by = blockIdx.y;   // 0..63

  const signed char* A1g = X1 + (size_t)(by * BM) * GK;
  const signed char* A2g = X2 + (size_t)(by * BM) * GK;
  const signed char* B1g = B1 + (size_t)(bx * BN) * GK;
  const signed char* B2g = B2 + (size_t)(bx * BN) * GK;

  // staging: wave w owns array w; pre-swizzled per-lane global offset
  const int srow = lane >> 2;
  const int schk = (lane & 3) ^ ((lane >> 3) & 3);
  const signed char* gw =
      (wave == 0 ? A1g : wave == 1 ? A2g : wave == 2 ? B1g : B2g) +
      (size_t)srow * GK + schk * 16;

  // read-side swizzled offsets (within one 32KB buffer)
  const int rl = lane & 15;
  const int fhalf = (lane >> 4) & 1;
  const int fck = lane >> 5;
  int aoff[2][2], boff[2][2];  // [mi|ni][ks]; level-2 arrays at +8192
#pragma unroll
  for (int mi = 0; mi < 2; ++mi)
#pragma unroll
    for (int ks = 0; ks < 2; ++ks) {
      int c = 2 * ks + fck;
      int slot = 4 * rl + (c ^ ((rl >> 1) & 3));
      aoff[mi][ks] = (wr * 4 + mi * 2 + fhalf) * 1024 + slot * 16;
      boff[mi][ks] = 16384 + (wc * 4 + mi * 2 + fhalf) * 1024 + slot * 16;
    }

  int16v acc_h[2][2], acc_c[2][2];
#pragma unroll
  for (int i = 0; i < 2; ++i)
#pragma unroll
    for (int j = 0; j < 2; ++j)
#pragma unroll
      for (int e = 0; e < 16; ++e) { acc_h[i][j][e] = 0; acc_c[i][j][e] = 0; }

  // fragment sets (register double buffer)
  int4v s0_a1[2][2], s0_a2[2][2], s0_b1[2][2], s0_b2[2][2];
  int4v s1_a1[2][2], s1_a2[2][2], s1_b1[2][2], s1_b2[2][2];

  // prologue: stage tiles 0,1,2 into buffers 0,1,2 (24 gloads/wave in flight)
#pragma unroll
  for (int t = 0; t < 3; ++t) {
    char* wb = sL + t * BUFSZ + wave * 8192;
    const signed char* gp = gw + (size_t)t * BK;
    STAGE8(wb, gp);
  }
  asm volatile("s_waitcnt vmcnt(16)" ::: "memory");  // tile 0 landed
  __builtin_amdgcn_s_barrier();
  RD16(s0_, sL);  // tile 0 -> set 0 (waited inside STEP(0))

#pragma unroll 1
  for (int i = 0; i < NT; i += 2) {
    STEP(i, s0_, s1_);
    STEP(i + 1, s1_, s0_);
  }

  // epilogue: C/D col=lane&31, row=(reg&3)+8*(reg>>2)+4*(lane>>5); apply sw1
  const int ecol = lane & 31;
  const int erow = 4 * (lane >> 5);
#pragma unroll
  for (int ni = 0; ni < 2; ++ni) {
    int col = bx * BN + wc * 64 + ni * 32 + ecol;
    float sw = sw1[col];
#pragma unroll
    for (int mi = 0; mi < 2; ++mi) {
#pragma unroll
      for (int reg = 0; reg < 16; ++reg) {
        int row = by * BM + wr * 64 + mi * 32 + (reg & 3) + 8 * (reg >> 2) + erow;
        float v = (float)acc_h[mi][ni][reg] + (float)acc_c[mi][ni][reg] * (1.0f / 254.0f);
        C[(size_t)row * MCOLS + col] = v * sw;
      }
    }
  }
}

// ---------------- row softmax: one wave per row, applies sx1[row] -----------
__global__ __launch_bounds__(256) void softmax_kernel(
    float* __restrict__ C, const float* __restrict__ sx1) {
  const int lane = threadIdx.x & 63;
  const int wv = threadIdx.x >> 6;
  const int row = blockIdx.x * 4 + wv;
  const float sx = sx1[row];
  float4* p = (float4*)(C + (size_t)row * MCOLS);

  float4 v[8];
#pragma unroll
  for (int j = 0; j < 8; ++j) {
    v[j] = p[j * 64 + lane];
    v[j].x *= sx; v[j].y *= sx; v[j].z *= sx; v[j].w *= sx;
  }

  float vmax = -3.4e38f;
#pragma unroll
  for (int j = 0; j < 8; ++j)
    vmax = fmaxf(vmax, fmaxf(fmaxf(v[j].x, v[j].y), fmaxf(v[j].z, v[j].w)));
#pragma unroll
  for (int off = 32; off > 0; off >>= 1)
    vmax = fmaxf(vmax, __shfl_xor(vmax, off));

  float sum = 0.f;
#pragma unroll
  for (int j = 0; j < 8; ++j) {
    v[j].x = __expf(v[j].x - vmax);
    v[j].y = __expf(v[j].y - vmax);
    v[j].z = __expf(v[j].z - vmax);
    v[j].w = __expf(v[j].w - vmax);
    sum += (v[j].x + v[j].y) + (v[j].z + v[j].w);
  }
#pragma unroll
  for (int off = 32; off > 0; off >>= 1)
    sum += __shfl_xor(sum, off);
  float inv = 1.0f / sum;

#pragma unroll
  for (int j = 0; j < 8; ++j) {
    v[j].x *= inv; v[j].y *= inv; v[j].z *= inv; v[j].w *= inv;
    p[j * 64 + lane] = v[j];
  }
}

// ---------------- launcher --------------------------------------------------
extern "C" void kernel_launch(void* const* d_in, const int* in_sizes, int n_in,
                              void* d_out, int out_size, void* d_ws, size_t ws_size,
                              hipStream_t stream) {
  const float* X      = (const float*)d_in[0];
  const float* weight = (const float*)d_in[1];
  const float* W1     = (const float*)d_in[2];
  const float* b1     = (const float*)d_in[3];
  const float* W2     = (const float*)d_in[4];
  const float* b2     = (const float*)d_in[5];
  const float* W3     = (const float*)d_in[6];
  const float* b3     = (const float*)d_in[7];
  float* out = (float*)d_out;

  const int N = 2048, M = 2048;
  const int Bdim = in_sizes[0] / N;   // 8192

  float* rowS = (float*)d_ws;
  float* part = rowS + 2048;
  float* sx1  = part + NCHUNK * 2048;
  float* sw1  = sx1 + 8192;
  float* Wt   = sw1 + 2048;
  signed char* X1 = (signed char*)(Wt + (size_t)M * N);
  signed char* X2 = X1 + (size_t)Bdim * N;
  signed char* B1q = X2 + (size_t)Bdim * N;
  signed char* B2q = B1q + (size_t)M * N;

  pre_kernel<<<CS_BLOCKS + RS_BLOCKS + Bdim, 256, 0, stream>>>(
      X, weight, X1, X2, sx1, part, rowS);

  nca_update_kernel<<<dim3(M / 32, N / 32), 256, 0, stream>>>(
      weight, part, rowS, W1, b1, W2, b2, W3, b3, Wt);

  bquant_kernel<<<M, 256, 0, stream>>>(Wt, B1q, B2q, sw1);

  gemm_kernel<<<dim3(M / BN, Bdim / BM), 256, 0, stream>>>(
      X1, X2, B1q, B2q, sw1, out);

  softmax_kernel<<<Bdim / 4, 256, 0, stream>>>(out, sx1);
}